// Round 18
// baseline (127.971 us; speedup 1.0000x reference)
//
#include <hip/hip_runtime.h>
#include <cstdint>
#include <cstddef>

// B=2, S=1024, D=512, NH=16 (chunk width), C=32 chunks.
// weights (C,B,S,S) fp32 = 256 MiB written once (fused, never re-read).
// out_pre scramble: (c,b,m,h) -> [c>>4][(c&15)*64 + (m>>4)][(m&15)*32 + b*16 + h]
// R18: single-QK attention. Wave pairs split the n-dim (wave = 16 rows x
// 512 n) so the bf16 e-cache (ep[64] u32) fits the 512-thread 128-VGPR cap.
// QK^T+exp computed ONCE; PV uses unnormalized e (inv applied to acc at the
// end, per-row inv via shfl); pass 2 = unpack+mul+store only.

typedef __attribute__((ext_vector_type(8)))  short    short8;   // 8 bf16 (4 VGPR)
typedef __attribute__((ext_vector_type(4)))  float    f32x4;    // 16x16 MFMA C/D
typedef __attribute__((ext_vector_type(4)))  unsigned u32x4;

union FragU { u32x4 u; short8 s; };

// bf16 round-to-nearest-even pack of two floats into one u32 (lo=a, hi=b)
__device__ __forceinline__ unsigned pk_bf16(float a, float b) {
    unsigned ua = __float_as_uint(a), ub = __float_as_uint(b);
    ua = (ua + 0x7fffu + ((ua >> 16) & 1u)) >> 16;
    ub = (ub + 0x7fffu + ((ub >> 16) & 1u)) >> 16;
    return ua | (ub << 16);
}
__device__ __forceinline__ unsigned short bf16_1(float a) {
    unsigned ua = __float_as_uint(a);
    return (unsigned short)((ua + 0x7fffu + ((ua >> 16) & 1u)) >> 16);
}

// ---------------------------------------------------------------------------
// MFMA NT GEMM (tile 128m x 64n, verified fragment discipline R12-R17).
// BF16OUT: store bf16 u16 (producer-side conversion for q/k/v).
// wscale: folded into staged W (0.25 for Wq -> q pre-scaled, exact).
// ---------------------------------------------------------------------------
template <bool BF16OUT>
__device__ __forceinline__ void gemm_nt_mfma_body(const float* __restrict__ X,
                                                  const float* __restrict__ W,
                                                  void* __restrict__ Pout,
                                                  float wscale)
{
    __shared__ unsigned Xs[128 * 17 * 4];  // 34 KB
    __shared__ unsigned Ws[64 * 17 * 4];   // 17 KB
    const int t  = threadIdx.x;
    const int m0 = blockIdx.y << 7;        // 128-row tile
    const int n0 = blockIdx.x << 6;        // 64-col tile
    const int wave = t >> 6, lane = t & 63;
    const int ml = lane & 15;              // A row / B col within 16
    const int g  = lane >> 4;              // k-group (0..3)

    f32x4 acc[2][4] = {{{0,0,0,0},{0,0,0,0},{0,0,0,0},{0,0,0,0}},
                       {{0,0,0,0},{0,0,0,0},{0,0,0,0},{0,0,0,0}}};

#pragma unroll 1
    for (int st = 0; st < 4; ++st) {
        if (st) __syncthreads();           // prior compute done before restage
#pragma unroll
        for (int rep = 0; rep < 8; ++rep) {
            int f  = rep * 256 + t;
            int kf = f & 15, r = f >> 4;
            const float* xr = X + (size_t)(m0 + r) * 512 + st * 128 + kf * 8;
            float4 a = *(const float4*)xr;
            float4 b = *(const float4*)(xr + 4);
            unsigned* dx = &Xs[(r * 17 + kf) * 4];
            dx[0] = pk_bf16(a.x, a.y); dx[1] = pk_bf16(a.z, a.w);
            dx[2] = pk_bf16(b.x, b.y); dx[3] = pk_bf16(b.z, b.w);
        }
#pragma unroll
        for (int rep = 0; rep < 4; ++rep) {
            int f  = rep * 256 + t;
            int kf = f & 15, r = f >> 4;
            const float* wr = W + (size_t)(n0 + r) * 512 + st * 128 + kf * 8;
            float4 c = *(const float4*)wr;
            float4 d = *(const float4*)(wr + 4);
            unsigned* dw = &Ws[(r * 17 + kf) * 4];
            dw[0] = pk_bf16(c.x * wscale, c.y * wscale);
            dw[1] = pk_bf16(c.z * wscale, c.w * wscale);
            dw[2] = pk_bf16(d.x * wscale, d.y * wscale);
            dw[3] = pk_bf16(d.z * wscale, d.w * wscale);
        }
        __syncthreads();
#pragma unroll
        for (int ks = 0; ks < 4; ++ks) {
            const int kf = ks * 4 + g;
            FragU a0, a1;
            a0.u = *(const u32x4*)&Xs[((wave * 32 + ml) * 17 + kf) * 4];
            a1.u = *(const u32x4*)&Xs[((wave * 32 + 16 + ml) * 17 + kf) * 4];
#pragma unroll
            for (int nf = 0; nf < 4; ++nf) {
                FragU bw;
                bw.u = *(const u32x4*)&Ws[((nf * 16 + ml) * 17 + kf) * 4];
                acc[0][nf] = __builtin_amdgcn_mfma_f32_16x16x32_bf16(
                    a0.s, bw.s, acc[0][nf], 0, 0, 0);
                acc[1][nf] = __builtin_amdgcn_mfma_f32_16x16x32_bf16(
                    a1.s, bw.s, acc[1][nf], 0, 0, 0);
            }
        }
    }
#pragma unroll
    for (int af = 0; af < 2; ++af)
#pragma unroll
        for (int nf = 0; nf < 4; ++nf)
#pragma unroll
            for (int r = 0; r < 4; ++r) {
                const int m = m0 + wave * 32 + af * 16 + g * 4 + r;
                const size_t idx = (size_t)m * 512 + n0 + nf * 16 + ml;
                if (BF16OUT)
                    ((unsigned short*)Pout)[idx] = bf16_1(acc[af][nf][r]);
                else
                    ((float*)Pout)[idx] = acc[af][nf][r];
            }
}

__global__ __launch_bounds__(256, 2) void proj3_kernel(
    const float* __restrict__ Q, const float* __restrict__ K, const float* __restrict__ V,
    const float* __restrict__ Wq, const float* __restrict__ Wk, const float* __restrict__ Wv,
    unsigned short* __restrict__ q, unsigned short* __restrict__ k,
    unsigned short* __restrict__ v)
{
    const float* X; const float* W; unsigned short* P; float ws;
    if (blockIdx.z == 0)      { X = Q; W = Wq; P = q; ws = 0.25f; }
    else if (blockIdx.z == 1) { X = K; W = Wk; P = k; ws = 1.0f; }
    else                      { X = V; W = Wv; P = v; ws = 1.0f; }
    gemm_nt_mfma_body<true>(X, W, P, ws);
}

__global__ __launch_bounds__(256, 2) void outproj_kernel(
    const float* __restrict__ att, const float* __restrict__ Wo, float* __restrict__ out)
{
    gemm_nt_mfma_body<false>(att, Wo, out, 1.0f);
}

// ---------------------------------------------------------------------------
// v14 single-QK MFMA attention. 512 threads = 8 waves = 4 wave-pairs.
// Wave pair p owns rows m0b + p*16 .. +15; wave half (wave&1) owns n-half.
// Pass 1 (per local nt, 32 iters): ka ds_read -> QK MFMA -> exp (ONCE) ->
//   cache bf16 e in ep[64] regs + pbuf -> PV MFMA with UNNORMALIZED e.
// Sums: wave shfl-reduce + cross-half LDS exchange -> inv (per-lane, row ml).
// Pass 2: unpack ep * inv -> float4 weights stores (no MFMA, no exp).
// acc: cross-half LDS exchange; scaled by per-row inv via shfl; half0 writes.
// LDS 79.5 KB -> 2 blocks/CU -> 4 waves/SIMD. Regs ~115 < 128 cap.
// ---------------------------------------------------------------------------
__global__ __launch_bounds__(512)
void attn_mfma_kernel(
    const unsigned short* __restrict__ q, const unsigned short* __restrict__ k,
    const unsigned short* __restrict__ v,
    float* __restrict__ wts, float* __restrict__ att)
{
    __shared__ unsigned ksF[64 * 128];    // 32 KB
    __shared__ unsigned vsT[16][514];     // 32.9 KB
    __shared__ unsigned pbuf[8][16][18];  // 9.2 KB per-wave P tiles
    __shared__ float    sumx[4][2][16];   // 0.5 KB cross-half row sums
    __shared__ float    accx[4][16][16];  // 4 KB cross-half PV partials

    const int t     = threadIdx.x;
    const int bid   = blockIdx.x;         // 1024 blocks
    const int strip = bid & 15;           // 16 strips of 64 m-rows
    const int cb    = bid >> 4;           // c*2 + b
    const int b     = cb & 1;
    const int c     = cb >> 1;
    const int m0b   = strip << 6;

    const unsigned short* kb = k + (size_t)b * 524288 + c * 16;
    const unsigned short* vb = v + (size_t)b * 524288 + c * 16;

    // ---- stage K as A-fragments: direct 16B copies (n 0..1023, g 0..1) ----
#pragma unroll
    for (int rep = 0; rep < 4; ++rep) {
        int f = rep * 512 + t;            // 0..2047
        int n = f >> 1, gg = f & 1;
        u32x4 kv = *(const u32x4*)(kb + (size_t)n * 512 + gg * 8);
        *(u32x4*)&ksF[(n >> 4) * 128 + ((n & 15) + (gg << 4)) * 4] = kv;
    }
    // ---- stage V as [h][n-pair]: 2x8B loads + bitmerge ----
#pragma unroll
    for (int rep = 0; rep < 4; ++rep) {
        int f = rep * 512 + t;            // p(0..511) x hq(0..3)
        int p = f >> 2, hq = f & 3;
        uint2 a  = *(const uint2*)(vb + (size_t)(2 * p)     * 512 + hq * 4);
        uint2 bb = *(const uint2*)(vb + (size_t)(2 * p + 1) * 512 + hq * 4);
        vsT[hq * 4 + 0][p] = (a.x & 0xffffu) | (bb.x << 16);
        vsT[hq * 4 + 1][p] = (a.x >> 16) | (bb.x & 0xffff0000u);
        vsT[hq * 4 + 2][p] = (a.y & 0xffffu) | (bb.y << 16);
        vsT[hq * 4 + 3][p] = (a.y >> 16) | (bb.y & 0xffff0000u);
    }
    __syncthreads();

    const int wave  = t >> 6, lane = t & 63;
    const int ml    = lane & 15;          // row (QK D col) / h (PV D col)
    const int g     = lane >> 4;          // k-group
    const int pair  = wave >> 1;          // wave-pair: rows m0b+pair*16..+15
    const int nhalf = wave & 1;           // n-half: n in [nhalf*512, +512)
    const int m0w   = m0b + pair * 16;

    // ---- Q fragment: direct 16B copy (0.25 pre-folded); k 16..31 zero ----
    FragU qf;
    if (g < 2) {
        qf.u = *(const u32x4*)(q + (size_t)b * 524288
                                 + (size_t)(m0w + ml) * 512 + c * 16 + g * 8);
    } else {
        qf.u = (u32x4){0, 0, 0, 0};
    }

    const f32x4 zero4 = {0.f, 0.f, 0.f, 0.f};

    // ---- pass 1: QK + exp ONCE; cache e; PV with unnormalized e ----
    float rs = 0.f;
    unsigned ep[64];
    f32x4 acc = zero4;
#pragma unroll
    for (int ip = 0; ip < 16; ++ip) {
#pragma unroll
        for (int sub = 0; sub < 2; ++sub) {
            const int i  = ip * 2 + sub;         // local nt 0..31
            const int nt = nhalf * 32 + i;       // global nt
            FragU ka;
            if (lane < 32) ka.u = *(const u32x4*)&ksF[nt * 128 + lane * 4];
            else           ka.u = (u32x4){0, 0, 0, 0};
            f32x4 st = __builtin_amdgcn_mfma_f32_16x16x32_bf16(ka.s, qf.s, zero4, 0, 0, 0);
            float e0 = __expf(st[0]);
            float e1 = __expf(st[1]);
            float e2 = __expf(st[2]);
            float e3 = __expf(st[3]);
            rs += (e0 + e1) + (e2 + e3);
            ep[i * 2]     = pk_bf16(e0, e1);
            ep[i * 2 + 1] = pk_bf16(e2, e3);
            unsigned* pb = &pbuf[wave][ml][sub * 8 + g * 2];
            pb[0] = ep[i * 2];
            pb[1] = ep[i * 2 + 1];
        }
        // PV over this 32-n block (unnormalized; same-wave LDS RAW in-order)
        const int ntg = nhalf * 16 + ip;
        FragU pa, vf;
        pa.u = *(const u32x4*)&pbuf[wave][ml][g * 4];
        vf.u = *(const u32x4*)&vsT[ml][ntg * 16 + g * 4];
        acc = __builtin_amdgcn_mfma_f32_16x16x32_bf16(pa.s, vf.s, acc, 0, 0, 0);
    }

    // ---- row sums: wave reduce + cross-half exchange -> inv ----
    rs += __shfl_xor(rs, 16);
    rs += __shfl_xor(rs, 32);
    if (lane < 16) sumx[pair][nhalf][lane] = rs;
    __syncthreads();
    const float inv = 1.0f / (rs + sumx[pair][nhalf ^ 1][ml]);

    // ---- cross-half PV partial exchange (half1 publishes) ----
    if (nhalf) {
#pragma unroll
        for (int r = 0; r < 4; ++r) accx[pair][g * 4 + r][ml] = acc[r];
    }
    __syncthreads();

    // ---- pass 2: weights stores from cached e (no MFMA, no exp) ----
    float* wrow = wts + (size_t)cb * 1048576 + (size_t)(m0w + ml) * 1024
                      + nhalf * 512;
#pragma unroll
    for (int i = 0; i < 32; ++i) {
        float a0 = __uint_as_float(ep[i * 2] << 16) * inv;
        float a1 = __uint_as_float(ep[i * 2] & 0xffff0000u) * inv;
        float a2 = __uint_as_float(ep[i * 2 + 1] << 16) * inv;
        float a3 = __uint_as_float(ep[i * 2 + 1] & 0xffff0000u) * inv;
        *(float4*)(wrow + i * 16 + g * 4) = make_float4(a0, a1, a2, a3);
    }

    // ---- att write (half0 waves): total acc * per-row inv, scrambled ----
    if (!nhalf) {
        const int b2 = c >> 4;
#pragma unroll
        for (int r = 0; r < 4; ++r) {
            const float tot  = acc[r] + accx[pair][g * 4 + r][ml];
            const float invr = __shfl(inv, g * 4 + r);
            const int m  = m0w + g * 4 + r;
            const int m2 = (c & 15) * 64 + (m >> 4);
            const int d2 = (m & 15) * 32 + b * 16 + ml;
            att[((size_t)b2 * 1024 + m2) * 512 + d2] = tot * invr;
        }
    }
}

// ---------------------------------------------------------------------------
extern "C" void kernel_launch(void* const* d_in, const int* in_sizes, int n_in,
                              void* d_out, int out_size, void* d_ws, size_t ws_size,
                              hipStream_t stream)
{
    (void)in_sizes; (void)n_in; (void)out_size; (void)ws_size;
    const float* Q  = (const float*)d_in[0];
    const float* K  = (const float*)d_in[1];
    const float* V  = (const float*)d_in[2];
    const float* Wq = (const float*)d_in[3];
    const float* Wk = (const float*)d_in[4];
    const float* Wv = (const float*)d_in[5];
    const float* Wo = (const float*)d_in[6];

    float* out = (float*)d_out;
    float* wts = out + 1048576;            // weights output region (64M floats)

    float* ws  = (float*)d_ws;
    unsigned short* q16 = (unsigned short*)ws;                   // 2 MB
    unsigned short* k16 = (unsigned short*)(ws + (1u << 19));    // 2 MB
    unsigned short* v16 = (unsigned short*)(ws + (1u << 20));    // 2 MB
    float* att = ws + 2 * (1u << 20);                            // 4 MB fp32

    proj3_kernel<<<dim3(8, 16, 3), 256, 0, stream>>>(Q, K, V, Wq, Wk, Wv,
                                                     q16, k16, v16);
    attn_mfma_kernel<<<1024, 512, 0, stream>>>(q16, k16, v16, wts, att);
    outproj_kernel<<<dim3(8, 16, 1), 256, 0, stream>>>(att, Wo, out);
}